// Round 10
// baseline (74.803 us; speedup 1.0000x reference)
//
#include <hip/hip_runtime.h>
#include <math.h>
#include <stdint.h>

#define NLEV 8
#define TSIZE 131072
#define TMASK (TSIZE - 1)

typedef float nfloat2 __attribute__((ext_vector_type(2)));

__device__ __forceinline__ void transform_pos(
    const float* __restrict__ positions, const float* __restrict__ c2ws,
    const float* __restrict__ aabb, int gid, int S,
    float& posx, float& posy, float& posz, bool& sel)
{
    int r = gid / S;
    const float* p = positions + (size_t)gid * 3;
    const float* c = c2ws + (size_t)r * 12;
    float px = p[0], py = p[1], pz = p[2];
    float c00 = c[0], c01 = c[1], c02 = c[2],  t0 = c[3];
    float c10 = c[4], c11 = c[5], c12 = c[6],  t1 = c[7];
    float c20 = c[8], c21 = c[9], c22 = c[10], t2 = c[11];

    // reference op order, no FMA contraction (selector boundary must match)
    float m0 = __fadd_rn(__fadd_rn(__fmul_rn(c00, px), __fmul_rn(c10, py)), __fmul_rn(c20, pz));
    float m1 = __fadd_rn(__fadd_rn(__fmul_rn(c01, px), __fmul_rn(c11, py)), __fmul_rn(c21, pz));
    float m2 = __fadd_rn(__fadd_rn(__fmul_rn(c02, px), __fmul_rn(c12, py)), __fmul_rn(c22, pz));
    float n0 = __fadd_rn(__fadd_rn(__fmul_rn(c00, t0), __fmul_rn(c10, t1)), __fmul_rn(c20, t2));
    float n1 = __fadd_rn(__fadd_rn(__fmul_rn(c01, t0), __fmul_rn(c11, t1)), __fmul_rn(c21, t2));
    float n2 = __fadd_rn(__fadd_rn(__fmul_rn(c02, t0), __fmul_rn(c12, t1)), __fmul_rn(c22, t2));
    float x0 = __fsub_rn(m0, n0);
    float x1 = __fsub_rn(m1, n1);
    float x2 = __fsub_rn(m2, n2);

    float a0x = aabb[0], a0y = aabb[1], a0z = aabb[2];
    float a1x = aabb[3], a1y = aabb[4], a1z = aabb[5];
    posx = __fdiv_rn(__fsub_rn(x0, a0x), __fsub_rn(a1x, a0x));
    posy = __fdiv_rn(__fsub_rn(x1, a0y), __fsub_rn(a1y, a0y));
    posz = __fdiv_rn(__fsub_rn(x2, a0z), __fsub_rn(a1z, a0z));
    sel = (posx > 0.f) & (posx < 1.f) & (posy > 0.f) & (posy < 1.f) & (posz > 0.f) & (posz < 1.f);
}

// ---------------- K0: transform once per sample ----------------
__global__ __launch_bounds__(256) void rif_xform(
    const float* __restrict__ positions,
    const float* __restrict__ c2ws,
    const float* __restrict__ aabb,
    float4* __restrict__ pos4,
    int total, int S)
{
    int gid = blockIdx.x * 256 + threadIdx.x;
    if (gid >= total) return;
    float posx, posy, posz; bool sel;
    transform_pos(positions, c2ws, aabb, gid, S, posx, posy, posz, sel);
    pos4[gid] = make_float4(posx, posy, posz, sel ? 1.f : 0.f);
}

// ---------------- K1: level-major encode, 2 samples/thread ----------------
// block = 256 threads = 256 samples x 2 levels; thread handles samples (sA, sA+128)
// for level (g or 7-g), g = blockIdx%4. Blocks round-robin XCDs -> each XCD
// touches 2 subtables (2 MB) -> L2-resident. 16 gathers in flight per thread.
__global__ __launch_bounds__(256) void rif_enc(
    const float4* __restrict__ pos4,
    const float* __restrict__ table,
    nfloat2* __restrict__ encf2,
    int total)
{
    int g     = blockIdx.x & 3;
    int chunk = blockIdx.x >> 2;
    int half  = threadIdx.x >> 7;
    int sl    = threadIdx.x & 127;
    int l     = half ? (7 - g) : g;
    int gidA  = chunk * 256 + sl;
    int gidB  = gidA + 128;

    float sc = (l == 0) ? 16.f : (l == 1) ? 28.f : (l == 2) ? 52.f : (l == 3) ? 95.f
             : (l == 4) ? 172.f : (l == 5) ? 312.f : (l == 6) ? 565.f : 1024.f;
    const float2* tab = (const float2*)table + (size_t)l * TSIZE;

    bool selA = false, selB = false;
    float4 ppA, ppB;
    if (gidA < total) { ppA = pos4[gidA]; selA = (ppA.w != 0.f); }
    if (gidB < total) { ppB = pos4[gidB]; selB = (ppB.w != 0.f); }
    if (!selA && !selB) return;

    float wxA, wyA, wzA, wxB, wyB, wzB;
    uint32_t hA[8], hB[8];

    if (selA) {
        float sx = ppA.x * sc, sy = ppA.y * sc, sz = ppA.z * sc;
        float fx = floorf(sx), fy = floorf(sy), fz = floorf(sz);
        wxA = sx - fx; wyA = sy - fy; wzA = sz - fz;
        uint32_t ix = (uint32_t)(int)fx, iy = (uint32_t)(int)fy, iz = (uint32_t)(int)fz;
        uint32_t hy0 = iy * 2654435761u, hy1 = hy0 + 2654435761u;
        uint32_t hz0 = iz * 805459861u,  hz1 = hz0 + 805459861u;
        #pragma unroll
        for (int cc = 0; cc < 8; ++cc) {
            uint32_t cx = (cc >> 2) & 1, cy = (cc >> 1) & 1, cz = cc & 1;
            hA[cc] = ((ix + cx) ^ (cy ? hy1 : hy0) ^ (cz ? hz1 : hz0)) & TMASK;
        }
    }
    if (selB) {
        float sx = ppB.x * sc, sy = ppB.y * sc, sz = ppB.z * sc;
        float fx = floorf(sx), fy = floorf(sy), fz = floorf(sz);
        wxB = sx - fx; wyB = sy - fy; wzB = sz - fz;
        uint32_t ix = (uint32_t)(int)fx, iy = (uint32_t)(int)fy, iz = (uint32_t)(int)fz;
        uint32_t hy0 = iy * 2654435761u, hy1 = hy0 + 2654435761u;
        uint32_t hz0 = iz * 805459861u,  hz1 = hz0 + 805459861u;
        #pragma unroll
        for (int cc = 0; cc < 8; ++cc) {
            uint32_t cx = (cc >> 2) & 1, cy = (cc >> 1) & 1, cz = cc & 1;
            hB[cc] = ((ix + cx) ^ (cy ? hy1 : hy0) ^ (cz ? hz1 : hz0)) & TMASK;
        }
    }

    // issue all (up to 16) gathers before any consumption
    float2 ftA[8], ftB[8];
    if (selA) {
        #pragma unroll
        for (int cc = 0; cc < 8; ++cc) ftA[cc] = tab[hA[cc]];
    }
    if (selB) {
        #pragma unroll
        for (int cc = 0; cc < 8; ++cc) ftB[cc] = tab[hB[cc]];
    }
    __builtin_amdgcn_sched_barrier(0);

    if (selA) {
        float ux = 1.f - wxA, uy = 1.f - wyA, uz = 1.f - wzA;
        float q00 = uy * uz, q01 = uy * wzA, q10 = wyA * uz, q11 = wyA * wzA;
        float f0, f1;
        f0 = ftA[0].x * (ux * q00); f1 = ftA[0].y * (ux * q00);
        f0 = fmaf(ftA[1].x, ux * q01, f0); f1 = fmaf(ftA[1].y, ux * q01, f1);
        f0 = fmaf(ftA[2].x, ux * q10, f0); f1 = fmaf(ftA[2].y, ux * q10, f1);
        f0 = fmaf(ftA[3].x, ux * q11, f0); f1 = fmaf(ftA[3].y, ux * q11, f1);
        f0 = fmaf(ftA[4].x, wxA * q00, f0); f1 = fmaf(ftA[4].y, wxA * q00, f1);
        f0 = fmaf(ftA[5].x, wxA * q01, f0); f1 = fmaf(ftA[5].y, wxA * q01, f1);
        f0 = fmaf(ftA[6].x, wxA * q10, f0); f1 = fmaf(ftA[6].y, wxA * q10, f1);
        f0 = fmaf(ftA[7].x, wxA * q11, f0); f1 = fmaf(ftA[7].y, wxA * q11, f1);
        nfloat2 v; v.x = f0; v.y = f1;
        __builtin_nontemporal_store(v, encf2 + (size_t)l * total + gidA);
    }
    if (selB) {
        float ux = 1.f - wxB, uy = 1.f - wyB, uz = 1.f - wzB;
        float q00 = uy * uz, q01 = uy * wzB, q10 = wyB * uz, q11 = wyB * wzB;
        float f0, f1;
        f0 = ftB[0].x * (ux * q00); f1 = ftB[0].y * (ux * q00);
        f0 = fmaf(ftB[1].x, ux * q01, f0); f1 = fmaf(ftB[1].y, ux * q01, f1);
        f0 = fmaf(ftB[2].x, ux * q10, f0); f1 = fmaf(ftB[2].y, ux * q10, f1);
        f0 = fmaf(ftB[3].x, ux * q11, f0); f1 = fmaf(ftB[3].y, ux * q11, f1);
        f0 = fmaf(ftB[4].x, wxB * q00, f0); f1 = fmaf(ftB[4].y, wxB * q00, f1);
        f0 = fmaf(ftB[5].x, wxB * q01, f0); f1 = fmaf(ftB[5].y, wxB * q01, f1);
        f0 = fmaf(ftB[6].x, wxB * q10, f0); f1 = fmaf(ftB[6].y, wxB * q10, f1);
        f0 = fmaf(ftB[7].x, wxB * q11, f0); f1 = fmaf(ftB[7].y, wxB * q11, f1);
        nfloat2 v; v.x = f0; v.y = f1;
        __builtin_nontemporal_store(v, encf2 + (size_t)l * total + gidB);
    }
}

// ---------------- K2: MLP + zero inactive ----------------
__global__ __launch_bounds__(256) void rif_mlp(
    const float4* __restrict__ pos4,
    const float* __restrict__ w1, const float* __restrict__ b1,
    const float* __restrict__ w2, const float* __restrict__ b2,
    const float* __restrict__ hw1, const float* __restrict__ hb1,
    const float* __restrict__ hw2, const float* __restrict__ hb2,
    float* __restrict__ out,
    const nfloat2* __restrict__ encf2,
    int total)
{
    int gid = blockIdx.x * 256 + threadIdx.x;
    if (gid >= total) return;
    if (pos4[gid].w == 0.f) { out[gid] = 0.f; return; }

    float enc[16];
    #pragma unroll
    for (int l = 0; l < 8; ++l) {
        nfloat2 v = __builtin_nontemporal_load(encf2 + (size_t)l * total + gid);
        enc[2 * l] = v.x; enc[2 * l + 1] = v.y;
    }

    float h1[32];
    #pragma unroll
    for (int j = 0; j < 32; ++j) h1[j] = b1[j];
    #pragma unroll
    for (int i = 0; i < 16; ++i) {
        float e = enc[i];
        #pragma unroll
        for (int j = 0; j < 32; ++j) h1[j] = fmaf(e, w1[i * 32 + j], h1[j]);
    }
    #pragma unroll
    for (int j = 0; j < 32; ++j) h1[j] = fmaxf(h1[j], 0.f);

    float h2[16];
    #pragma unroll
    for (int j = 0; j < 16; ++j) h2[j] = b2[j];
    #pragma unroll
    for (int i = 0; i < 32; ++i) {
        float e = h1[i];
        #pragma unroll
        for (int j = 0; j < 16; ++j) h2[j] = fmaf(e, w2[i * 16 + j], h2[j]);
    }

    float o = hb2[0];
    #pragma unroll
    for (int j = 0; j < 64; ++j) {
        float acc = hb1[j];
        #pragma unroll
        for (int i = 0; i < 16; ++i) acc = fmaf(h2[i], hw1[i * 64 + j], acc);
        o = fmaf(fmaxf(acc, 0.f), hw2[j], o);
    }

    float x = o - 5.0f;
    out[gid] = 1.0f / (1.0f + expf(-x));
}

// ---------------- Fallback: fused kernel (if ws too small) ----------------
__global__ __launch_bounds__(256, 2) void rif_fused(
    const float* __restrict__ positions,
    const float* __restrict__ c2ws,
    const float* __restrict__ aabb,
    const float* __restrict__ table,
    const float* __restrict__ w1, const float* __restrict__ b1,
    const float* __restrict__ w2, const float* __restrict__ b2,
    const float* __restrict__ hw1, const float* __restrict__ hb1,
    const float* __restrict__ hw2, const float* __restrict__ hb2,
    float* __restrict__ out, int total, int S)
{
    int gid = blockIdx.x * 256 + threadIdx.x;
    if (gid >= total) return;
    float posx, posy, posz; bool sel;
    transform_pos(positions, c2ws, aabb, gid, S, posx, posy, posz, sel);
    if (!sel) { out[gid] = 0.f; return; }

    const float kScale[8] = {16.f, 28.f, 52.f, 95.f, 172.f, 312.f, 565.f, 1024.f};
    float enc[16];
    #pragma unroll
    for (int l = 0; l < NLEV; ++l) {
        float sc = kScale[l];
        float sx = posx * sc, sy = posy * sc, sz = posz * sc;
        float fx = floorf(sx), fy = floorf(sy), fz = floorf(sz);
        float wx = sx - fx, wy = sy - fy, wz = sz - fz;
        uint32_t ix = (uint32_t)(int)fx, iy = (uint32_t)(int)fy, iz = (uint32_t)(int)fz;
        uint32_t hy0 = iy * 2654435761u, hy1 = hy0 + 2654435761u;
        uint32_t hz0 = iz * 805459861u,  hz1 = hz0 + 805459861u;
        const float2* tab = (const float2*)table + (size_t)l * TSIZE;
        float f0 = 0.f, f1 = 0.f;
        #pragma unroll
        for (int cc = 0; cc < 8; ++cc) {
            uint32_t cx = (cc >> 2) & 1, cy = (cc >> 1) & 1, cz = cc & 1;
            uint32_t hh = ((ix + cx) ^ (cy ? hy1 : hy0) ^ (cz ? hz1 : hz0)) & TMASK;
            float wgt = (cx ? wx : 1.f - wx) * (cy ? wy : 1.f - wy) * (cz ? wz : 1.f - wz);
            float2 ftv = tab[hh];
            f0 = fmaf(ftv.x, wgt, f0);
            f1 = fmaf(ftv.y, wgt, f1);
        }
        enc[2 * l] = f0;
        enc[2 * l + 1] = f1;
    }

    float h1[32];
    #pragma unroll
    for (int j = 0; j < 32; ++j) h1[j] = b1[j];
    #pragma unroll
    for (int i = 0; i < 16; ++i) {
        float e = enc[i];
        #pragma unroll
        for (int j = 0; j < 32; ++j) h1[j] = fmaf(e, w1[i * 32 + j], h1[j]);
    }
    #pragma unroll
    for (int j = 0; j < 32; ++j) h1[j] = fmaxf(h1[j], 0.f);

    float h2[16];
    #pragma unroll
    for (int j = 0; j < 16; ++j) h2[j] = b2[j];
    #pragma unroll
    for (int i = 0; i < 32; ++i) {
        float e = h1[i];
        #pragma unroll
        for (int j = 0; j < 16; ++j) h2[j] = fmaf(e, w2[i * 16 + j], h2[j]);
    }

    float o = hb2[0];
    #pragma unroll
    for (int j = 0; j < 64; ++j) {
        float acc = hb1[j];
        #pragma unroll
        for (int i = 0; i < 16; ++i) acc = fmaf(h2[i], hw1[i * 64 + j], acc);
        o = fmaf(fmaxf(acc, 0.f), hw2[j], o);
    }

    float x = o - 5.0f;
    out[gid] = 1.0f / (1.0f + expf(-x));
}

extern "C" void kernel_launch(void* const* d_in, const int* in_sizes, int n_in,
                              void* d_out, int out_size, void* d_ws, size_t ws_size,
                              hipStream_t stream) {
    const float* positions = (const float*)d_in[0];
    const float* c2ws      = (const float*)d_in[1];
    const float* aabb      = (const float*)d_in[2];
    const float* table     = (const float*)d_in[3];
    const float* w1  = (const float*)d_in[4];
    const float* b1  = (const float*)d_in[5];
    const float* w2  = (const float*)d_in[6];
    const float* b2  = (const float*)d_in[7];
    const float* hw1 = (const float*)d_in[8];
    const float* hb1 = (const float*)d_in[9];
    const float* hw2 = (const float*)d_in[10];
    const float* hb2 = (const float*)d_in[11];

    int R = in_sizes[1] / 12;
    int total = in_sizes[0] / 3;
    int S = total / R;

    size_t enc_bytes  = (size_t)total * 8 * sizeof(nfloat2);
    size_t pos_bytes  = (size_t)total * sizeof(float4);
    size_t needed = enc_bytes + pos_bytes;
    if (ws_size >= needed) {
        nfloat2* encf2 = (nfloat2*)d_ws;
        float4*  pos4  = (float4*)((char*)d_ws + enc_bytes);

        int blocks0 = (total + 255) / 256;
        hipLaunchKernelGGL(rif_xform, dim3(blocks0), dim3(256), 0, stream,
                           positions, c2ws, aabb, pos4, total, S);

        int nchunks = (total + 255) / 256;   // 256 samples x 2 levels per block
        hipLaunchKernelGGL(rif_enc, dim3(nchunks * 4), dim3(256), 0, stream,
                           pos4, table, encf2, total);

        hipLaunchKernelGGL(rif_mlp, dim3(blocks0), dim3(256), 0, stream,
                           pos4, w1, b1, w2, b2, hw1, hb1, hw2, hb2,
                           (float*)d_out, encf2, total);
    } else {
        int blocks = (total + 255) / 256;
        hipLaunchKernelGGL(rif_fused, dim3(blocks), dim3(256), 0, stream,
                           positions, c2ws, aabb, table,
                           w1, b1, w2, b2, hw1, hb1, hw2, hb2,
                           (float*)d_out, total, S);
    }
}